// Round 5
// baseline (302.853 us; speedup 1.0000x reference)
//
#include <hip/hip_runtime.h>

typedef float f4 __attribute__((ext_vector_type(4)));
typedef short s4 __attribute__((ext_vector_type(4)));
typedef short s8 __attribute__((ext_vector_type(8)));

#define HWD    1024
#define THW    8192
#define CVD    512
#define MT     32     // m per block
#define NRANGE 1024   // n per block
#define SUBS   32     // iters (32 n each)
#define AFP    36     // padded row length (shorts)

#define MFMA16 __builtin_amdgcn_mfma_f32_16x16x32_bf16

__device__ __forceinline__ unsigned cvtpk(float a, float b) {
    unsigned r;
    asm volatile("v_cvt_pk_bf16_f32 %0, %1, %2" : "=v"(r) : "v"(a), "v"(b));
    return r;   // lo16 = bf16(a), hi16 = bf16(b)
}
__device__ __forceinline__ float ubits(unsigned u) {
    return __builtin_bit_cast(float, u);
}
__device__ __forceinline__ s8 frag2(const short* p) {
    return __builtin_shufflevector(*(const s4*)p, *(const s4*)(p + 4), 0,1,2,3,4,5,6,7);
}

// ============ combined prep: mv->bf16 hi/lo | out init | feat rows ============
__global__ __launch_bounds__(256)
void mr_prep(const float* __restrict__ mv, const float* __restrict__ qv,
             const float* __restrict__ mk,
             short* __restrict__ mvH, short* __restrict__ mvL,
             short* __restrict__ ftH, short* __restrict__ ftL,
             float* __restrict__ out)
{
    __shared__ float mkT[16][260];
    const int bid = blockIdx.x, t = threadIdx.x;
    if (bid < 8192) {
        // ---- mv fp32 -> bf16 hi/lo (2,097,152 f4 elements) ----
        int i = bid * 256 + t;
        f4 v = ((const f4*)mv)[i];
        unsigned h01 = cvtpk(v[0], v[1]);
        unsigned h23 = cvtpk(v[2], v[3]);
        float f0 = ubits(h01 << 16), f1 = ubits(h01 & 0xffff0000u);
        float f2 = ubits(h23 << 16), f3 = ubits(h23 & 0xffff0000u);
        unsigned l01 = cvtpk(v[0] - f0, v[1] - f1);
        unsigned l23 = cvtpk(v[2] - f2, v[3] - f3);
        ((uint2*)mvH)[i] = make_uint2(h01, h23);
        ((uint2*)mvL)[i] = make_uint2(l01, l23);
    } else if (bid < 10240) {
        // ---- out init: zero mem half, copy qv half ----
        int idx = (bid - 8192) * 256 + t;
        int b = idx >> 18, r = idx & 262143, ch = r >> 8;
        f4 v = f4{0.f, 0.f, 0.f, 0.f};
        if (ch >= CVD) v = ((const f4*)qv)[(b << 17) + ((ch - CVD) << 8) + (r & 255)];
        ((f4*)out)[idx] = v;
    } else {
        // ---- feat rows: (mk^3, mk) bf16 hi/lo, k-contiguous ----
        const int fbid = bid - 10240;                 // 0..255
        const int chunk = fbid & 31, h = (fbid >> 5) & 3, b = fbid >> 7;
        const float* src = mk + (size_t)(b * 64 + h * 16) * THW + chunk * 256;
#pragma unroll
        for (int i = 0; i < 4; ++i) {
            int q = t + 256 * i;
            int c = q >> 6, j = q & 63;
            *(f4*)&mkT[c][j * 4] = *(const f4*)(src + (size_t)c * THW + j * 4);
        }
        __syncthreads();
        unsigned uH[16], uL[16];
#pragma unroll
        for (int c = 0; c < 16; ++c) {
            float x = mkT[c][t];
            float x3 = x * x * x;
            unsigned hh = cvtpk(x3, x);
            float r3 = x3 - ubits(hh << 16);
            float r1 = x  - ubits(hh & 0xffff0000u);
            uH[c] = hh;
            uL[c] = cvtpk(r3, r1);
        }
        size_t row = ((size_t)(b * 4 + h) * THW + chunk * 256 + t) * 32;
        uint4* dH = (uint4*)(ftH + row);
        uint4* dL = (uint4*)(ftL + row);
#pragma unroll
        for (int k = 0; k < 4; ++k) {
            dH[k] = make_uint4(uH[4*k], uH[4*k+1], uH[4*k+2], uH[4*k+3]);
            dL[k] = make_uint4(uL[4*k], uL[4*k+1], uL[4*k+2], uL[4*k+3]);
        }
    }
}

// ============ fused main kernel: 4 waves, 1024 blocks ============
__global__ __launch_bounds__(256, 4)
void mr_main(const float* __restrict__ qk, const float* __restrict__ qe,
             const float* __restrict__ ms,
             const short* __restrict__ mvH, const short* __restrict__ mvL,
             const short* __restrict__ ftH, const short* __restrict__ ftL,
             float* __restrict__ out)
{
    union SM {
        struct { short wH[4][MT][AFP]; } su;                         // 9216 B (setup only)
        struct { short aff[2][2][MT][AFP]; float msv[NRANGE]; } mn;  // 9216 + 4096 B
    };
    __shared__ __align__(16) SM sm;
    __shared__ __align__(16) short wLs[4][MT][AFP];   // 9216 B, persists
    __shared__ float bS[4][MT];                        // 512 B

    // bijective XCD swizzle: 128 consecutive blocks (one n-chunk) per XCD
    const int bid  = blockIdx.x;
    const int wid  = (bid & 7) * 128 + (bid >> 3);
    const int nc   = wid >> 7;
    const int rest = wid & 127;
    const int mt0  = rest & 31;
    const int hp   = (rest >> 5) & 1;
    const int b    = rest >> 6;
    const int m0   = mt0 * MT;
    const int n0   = nc * NRANGE;

    const int t  = threadIdx.x;
    const int wv = t >> 6, l = t & 63, lr = l & 15, lg = l >> 4;
    const int nt = wv & 1, mq = wv >> 1;     // sim roles: (n-half, m-half)
    const int hl = wv & 1, cvh = wv >> 1;    // readout roles: (local head, cv-half)

    // ---- setup: weights (hi->LDS tmp, lo->LDS persist) + bias ----
    if (t < 128) {
        const int h = t >> 5, m = t & 31;
        const float* qkp = qk + (size_t)(b * 64 + h * 16) * HWD + m0 + m;
        const float* qep = qe + (size_t)(b * 64 + h * 16) * HWD + m0 + m;
        float bias = 0.f;
#pragma unroll
        for (int c = 0; c < 16; ++c) {
            float kv = qkp[(size_t)c * HWD];
            float ev = qep[(size_t)c * HWD];
            float w0 = -ev, w1 = 2.f * kv * ev;
            unsigned hh = cvtpk(w0, w1);
            float r0 = w0 - ubits(hh << 16);
            float r1 = w1 - ubits(hh & 0xffff0000u);
            *(unsigned*)&sm.su.wH[h][m][2 * c] = hh;
            *(unsigned*)&wLs[h][m][2 * c]      = cvtpk(r0, r1);
            bias -= ev * kv * kv * kv;
        }
        bS[h][m] = bias;
    }
    __syncthreads();

    // extract loop-invariant w-hi fragments + bias into registers
    s8 wHr[4];
    float biasr[4];
#pragma unroll
    for (int h = 0; h < 4; ++h) {
        wHr[h]   = frag2(&sm.su.wH[h][mq * 16 + lr][lg * 8]);
        biasr[h] = bS[h][mq * 16 + lr];
    }
    // ms staging (disjoint LDS region from wH — no barrier needed before)
    ((f4*)sm.mn.msv)[t] = ((const f4*)(ms + (size_t)b * THW + n0))[t];
    __syncthreads();

    f4 acc[4][2];
#pragma unroll
    for (int ct = 0; ct < 4; ++ct) {
        acc[ct][0] = f4{0.f, 0.f, 0.f, 0.f};
        acc[ct][1] = f4{0.f, 0.f, 0.f, 0.f};
    }

    const size_t fstep  = (size_t)THW * 32;
    const short* fbaseH = ftH + ((size_t)(b * 4) * THW + n0 + nt * 16 + lr) * 32 + lg * 8;
    const short* fbaseL = ftL + ((size_t)(b * 4) * THW + n0 + nt * 16 + lr) * 32 + lg * 8;
    const size_t abase0 = ((size_t)(b * CVD + hp * 256 + hl * 128 + cvh * 64 + lr)) * THW
                          + n0 + lg * 8;

    for (int s = 0; s < SUBS; ++s) {
        const int ns = s * 32;

        // ===== sim: per-head MFMA (bias in C-in), softmax in-register =====
        f4 sacc[4];
#pragma unroll
        for (int h = 0; h < 4; ++h) {
            s8 fH = *(const s8*)(fbaseH + (size_t)h * fstep + (size_t)ns * 32);
            s8 fL = *(const s8*)(fbaseL + (size_t)h * fstep + (size_t)ns * 32);
            s8 wL = frag2(&wLs[h][mq * 16 + lr][lg * 8]);
            f4 sa = f4{biasr[h], biasr[h], biasr[h], biasr[h]};
            sa = MFMA16(fH, wHr[h], sa, 0, 0, 0);
            sa = MFMA16(fL, wHr[h], sa, 0, 0, 0);
            sa = MFMA16(fH, wL,     sa, 0, 0, 0);
            sacc[h] = sa;
        }

        // issue readout A-loads (latency hides under softmax + barrier)
        s8 aHr[4], aLr[4];
#pragma unroll
        for (int ct = 0; ct < 4; ++ct) {
            size_t ao = abase0 + (size_t)ct * 16 * THW + ns;
            aHr[ct] = *(const s8*)(mvH + ao);
            aLr[ct] = *(const s8*)(mvL + ao);
        }

        // softmax over heads (in-lane)
        f4 msv4 = *(const f4*)&sm.mn.msv[ns + nt * 16 + lg * 4];
        float a0[4], a1[4];
#pragma unroll
        for (int r = 0; r < 4; ++r) {
            const float sc = msv4[r] * 0.125f;
            float x0 = sacc[0][r] * sc, x1 = sacc[1][r] * sc;
            float x2 = sacc[2][r] * sc, x3 = sacc[3][r] * sc;
            float mx = fmaxf(fmaxf(x0, x1), fmaxf(x2, x3));
            float e0 = __expf(x0 - mx), e1 = __expf(x1 - mx);
            float e2 = __expf(x2 - mx), e3 = __expf(x3 - mx);
            float rin = 1.f / (e0 + e1 + e2 + e3);
            a0[r] = (hp ? e2 : e0) * rin;
            a1[r] = (hp ? e3 : e1) * rin;
        }
        // pack to bf16 hi/lo via cvt_pk (decomposition exact by construction)
        unsigned h001 = cvtpk(a0[0], a0[1]), h023 = cvtpk(a0[2], a0[3]);
        unsigned h101 = cvtpk(a1[0], a1[1]), h123 = cvtpk(a1[2], a1[3]);
        unsigned l001 = cvtpk(a0[0] - ubits(h001 << 16), a0[1] - ubits(h001 & 0xffff0000u));
        unsigned l023 = cvtpk(a0[2] - ubits(h023 << 16), a0[3] - ubits(h023 & 0xffff0000u));
        unsigned l101 = cvtpk(a1[0] - ubits(h101 << 16), a1[1] - ubits(h101 & 0xffff0000u));
        unsigned l123 = cvtpk(a1[2] - ubits(h123 << 16), a1[3] - ubits(h123 & 0xffff0000u));
        {
            const int mrow = mq * 16 + lr, nn = nt * 16 + lg * 4;
            *(uint2*)&sm.mn.aff[0][0][mrow][nn] = make_uint2(h001, h023);
            *(uint2*)&sm.mn.aff[1][0][mrow][nn] = make_uint2(l001, l023);
            *(uint2*)&sm.mn.aff[0][1][mrow][nn] = make_uint2(h101, h123);
            *(uint2*)&sm.mn.aff[1][1][mrow][nn] = make_uint2(l101, l123);
        }
        __syncthreads();

        // ===== readout: 3-product hi/lo MFMA =====
        s8 bH[2], bL[2];
#pragma unroll
        for (int mt = 0; mt < 2; ++mt) {
            bH[mt] = frag2(&sm.mn.aff[0][hl][mt * 16 + lr][lg * 8]);
            bL[mt] = frag2(&sm.mn.aff[1][hl][mt * 16 + lr][lg * 8]);
        }
#pragma unroll
        for (int ct = 0; ct < 4; ++ct)
#pragma unroll
            for (int mt = 0; mt < 2; ++mt) {
                acc[ct][mt] = MFMA16(aHr[ct], bH[mt], acc[ct][mt], 0, 0, 0);
                acc[ct][mt] = MFMA16(aLr[ct], bH[mt], acc[ct][mt], 0, 0, 0);
                acc[ct][mt] = MFMA16(aHr[ct], bL[mt], acc[ct][mt], 0, 0, 0);
            }
        __syncthreads();
    }

    // ---- epilogue: combine n-chunk partials via hw fp32 atomics ----
    float* ob = out + (size_t)b * (2 * CVD * HWD);
#pragma unroll
    for (int ct = 0; ct < 4; ++ct)
#pragma unroll
        for (int mt = 0; mt < 2; ++mt)
#pragma unroll
            for (int r = 0; r < 4; ++r) {
                const int cv = hp * 256 + hl * 128 + cvh * 64 + ct * 16 + lg * 4 + r;
                const int m  = m0 + mt * 16 + lr;
#if defined(__HIP_PLATFORM_AMD__)
                unsafeAtomicAdd(ob + (size_t)cv * HWD + m, acc[ct][mt][r]);
#else
                atomicAdd(ob + (size_t)cv * HWD + m, acc[ct][mt][r]);
#endif
            }
}

extern "C" void kernel_launch(void* const* d_in, const int* in_sizes, int n_in,
                              void* d_out, int out_size, void* d_ws, size_t ws_size,
                              hipStream_t stream) {
    (void)in_sizes; (void)n_in; (void)out_size; (void)ws_size;
    const float* mk = (const float*)d_in[0];
    const float* qk = (const float*)d_in[1];
    const float* ms = (const float*)d_in[2];
    const float* qe = (const float*)d_in[3];
    const float* mv = (const float*)d_in[4];
    const float* qv = (const float*)d_in[5];
    float* out = (float*)d_out;

    // ws layout: mvH 16MiB | mvL 16MiB | ftH 4MiB | ftL 4MiB  (total 40 MiB)
    short* mvH = (short*)d_ws;
    short* mvL = (short*)((char*)d_ws + 16777216);
    short* ftH = (short*)((char*)d_ws + 33554432);
    short* ftL = (short*)((char*)d_ws + 37748736);

    mr_prep<<<10496, 256, 0, stream>>>(mv, qv, mk, mvH, mvL, ftH, ftL, out);
    mr_main<<<1024, 256, 0, stream>>>(qk, qe, ms, mvH, mvL, ftH, ftL, out);
}